// Round 19
// baseline (365.735 us; speedup 1.0000x reference)
//
#include <hip/hip_runtime.h>
#include <math.h>

typedef int   i32x4 __attribute__((ext_vector_type(4)));

#define NROWS 16384
#define DIMS  512
#define KC    8192
#define QCLIP 4.5f
#define DELTA_INT 1992        // ceil(5.0 / (2*(4.5/127)^2)) grid units
#define IBIAS 16777216        // 2^24 bias so keys are non-negative

__device__ inline unsigned fkey(float v) {
    unsigned u = __float_as_uint(v);
    return (u & 0x80000000u) ? ~u : (u | 0x80000000u);
}
__device__ inline unsigned umin_(unsigned a, unsigned b) { return a < b ? a : b; }
__device__ inline unsigned umax_(unsigned a, unsigned b) { return a > b ? a : b; }

// ---------------------------------------------------------------------------
// K0: fused prep (R13-R15-proven numerics). blocks [0,512): quantize z ->
// i8 panels; [512,768): quantize emb; [768,2816): emb row sum-of-squares in
// fp64 -> esf (f32) and esq (int grid). Blocks [0,32) zero the histogram;
// block 0 zeroes the done flag.
// Packed i8 layout (bytes): p*131072 + s*16384 + c*16, chunk c = f*64+lg*16+rr.
// 1KB fragment chunk read at +lane*16 is lane-linear.
// ---------------------------------------------------------------------------
__global__ __launch_bounds__(256)
void prep_kernel(const float* __restrict__ z, const float* __restrict__ emb,
                 signed char* __restrict__ zi8, signed char* __restrict__ ei8,
                 float* __restrict__ esf, int* __restrict__ esq,
                 int* __restrict__ counts, int* __restrict__ done)
{
    const float QS = 127.0f / QCLIP;
    int b = blockIdx.x, t = threadIdx.x;
    if (b == 0 && t == 0) *done = 0;
    if (b < 768) {
        if (b < 32) counts[b * 256 + t] = 0;
        const float* src;
        signed char* dst;
        int pb;
        if (b < 512) { src = z;   dst = zi8; pb = b; }
        else         { src = emb; dst = ei8; pb = b - 512; }
        int p = pb >> 3, s = pb & 7;
        signed char* dbase = dst + (size_t)p * 131072 + s * 16384;
        #pragma unroll
        for (int q = 0; q < 4; ++q) {
            int c = q * 256 + t;
            int f = c >> 6, lg = (c >> 4) & 3, rr = c & 15;
            int row = p * 256 + f * 16 + rr;
            const float* sp = src + (size_t)row * DIMS + s * 64 + lg * 16;
            float4 v0 = *(const float4*)(sp + 0);
            float4 v1 = *(const float4*)(sp + 4);
            float4 v2 = *(const float4*)(sp + 8);
            float4 v3 = *(const float4*)(sp + 12);
            float vv[16] = {v0.x, v0.y, v0.z, v0.w, v1.x, v1.y, v1.z, v1.w,
                            v2.x, v2.y, v2.z, v2.w, v3.x, v3.y, v3.z, v3.w};
            unsigned w[4];
            #pragma unroll
            for (int k = 0; k < 4; ++k) {
                unsigned r = 0;
                #pragma unroll
                for (int e = 0; e < 4; ++e) {
                    int qv = __float2int_rn(
                        fminf(fmaxf(vv[k * 4 + e] * QS, -127.f), 127.f));
                    r |= (unsigned)(qv & 255) << (e * 8);
                }
                w[k] = r;
            }
            *(i32x4*)(dbase + c * 16) =
                (i32x4){(int)w[0], (int)w[1], (int)w[2], (int)w[3]};
        }
    } else {
        int b2 = b - 768;
        int w = b2 * 4 + (t >> 6);
        int lane = t & 63;
        const float* r = emb + (size_t)w * DIMS;
        float4 v0 = *(const float4*)(r + lane * 4);
        float4 v1 = *(const float4*)(r + 256 + lane * 4);
        double s = (double)v0.x * v0.x + (double)v0.y * v0.y +
                   (double)v0.z * v0.z + (double)v0.w * v0.w +
                   (double)v1.x * v1.x + (double)v1.y * v1.y +
                   (double)v1.z * v1.z + (double)v1.w * v1.w;
        #pragma unroll
        for (int off = 32; off; off >>= 1) s += __shfl_down(s, off);
        if (lane == 0) {
            esf[w] = (float)s;
            const double grid = 2.0 * (QCLIP / 127.0) * (QCLIP / 127.0);
            esq[w] = (int)(s / grid + 0.5) + IBIAS;
        }
    }
}

// ---------------------------------------------------------------------------
// K1: i8 screen GEMM + per-(row, 128-col-block) top-2, INTEGER keys.
// Measured optimum (R14/R15, unchanged): 256x128 block, 4 waves 2Mx2N,
// wave tile 128x64, mfma_i32_16x16x64_i8, 8 K-steps, dbuf 48KB, 2 blocks/CU,
// bx on the fast grid axis. Fragment reads lane-linear: conflict-free.
// Epilogue: key = (esq[col] - dot) << 7 | col_local. tab u64 = k1<<32 | k2.
// ---------------------------------------------------------------------------
__global__ __launch_bounds__(256, 2)
void screen_kernel(const char* __restrict__ zq, const char* __restrict__ eq,
                   const int* __restrict__ esq,
                   unsigned long long* __restrict__ tab)
{
    __shared__ char smem[67584];   // dbuf 2x24KB; epilogue table 66KB

    const int t    = threadIdx.x;
    const int lane = t & 63;
    const int wave = t >> 6;
    const int lg   = lane >> 4;
    const int lr   = lane & 15;
    const int wm   = wave >> 1;      // 0..1 row half (128 rows)
    const int wn   = wave & 1;       // 0..1 col half (64 cols)
    const int bx   = blockIdx.x;     // row block 0..63 (FAST dim)
    const int by   = blockIdx.y;     // col block 0..63 (slow dim)

    const char* gA = zq + (size_t)bx * 131072;
    const char* gB = eq + (size_t)(by >> 1) * 131072 + (by & 1) * 8192;

    i32x4 acc[8][4];
    #pragma unroll
    for (int i = 0; i < 8; ++i)
        #pragma unroll
        for (int j = 0; j < 4; ++j)
            acc[i][j] = (i32x4){0, 0, 0, 0};

    typedef const __attribute__((address_space(1))) unsigned int gq_t;
    typedef __attribute__((address_space(3))) unsigned int lq_t;
    #define STAGE(dstbuf, s)                                                  \
    {                                                                         \
        const char* gsA = gA + (size_t)(s) * 16384;                          \
        const char* gsB = gB + (size_t)(s) * 16384;                          \
        _Pragma("unroll")                                                     \
        for (int k = 0; k < 4; ++k) {                                        \
            int off = k * 4096 + wave * 1024;                                \
            __builtin_amdgcn_global_load_lds(                                 \
                (gq_t*)(gsA + off + lane * 16),                               \
                (lq_t*)((dstbuf) + off), 16, 0, 0);                           \
        }                                                                     \
        _Pragma("unroll")                                                     \
        for (int k = 0; k < 2; ++k) {                                        \
            int off = k * 4096 + wave * 1024;                                \
            __builtin_amdgcn_global_load_lds(                                 \
                (gq_t*)(gsB + off + lane * 16),                               \
                (lq_t*)((dstbuf) + 16384 + off), 16, 0, 0);                   \
        }                                                                     \
    }
    #define COMPUTE(buf)                                                      \
    {                                                                         \
        const char* Ab = (buf) + (wm * 8) * 1024 + lane * 16;                 \
        const char* Bb = (buf) + 16384 + (wn * 4) * 1024 + lane * 16;         \
        i32x4 af[8], bf[4];                                                   \
        _Pragma("unroll")                                                     \
        for (int i = 0; i < 8; ++i) af[i] = *(const i32x4*)(Ab + i * 1024);   \
        _Pragma("unroll")                                                     \
        for (int j = 0; j < 4; ++j) bf[j] = *(const i32x4*)(Bb + j * 1024);   \
        _Pragma("unroll")                                                     \
        for (int i = 0; i < 8; ++i)                                           \
            _Pragma("unroll")                                                 \
            for (int j = 0; j < 4; ++j)                                       \
                acc[i][j] = __builtin_amdgcn_mfma_i32_16x16x64_i8(            \
                    af[i], bf[j], acc[i][j], 0, 0, 0);                        \
    }

    char* p0 = smem;
    char* p1 = smem + 24576;
    STAGE(p0, 0);
    __syncthreads();

    #pragma unroll 1
    for (int s = 0; s < 8; s += 2) {
        STAGE(p1, s + 1);
        COMPUTE(p0);
        __syncthreads();
        if (s + 2 < 8) STAGE(p0, s + 2);
        COMPUTE(p1);
        __syncthreads();
    }

    // ---- epilogue pass 1: per-thread top-2-of-4, integer keys ----
    unsigned long long* mb = (unsigned long long*)smem;  // stride 33/row
    int      esq_j[4];
    unsigned col_j[4];
    #pragma unroll
    for (int j = 0; j < 4; ++j) {
        int cl = wn * 64 + j * 16 + lr;
        esq_j[j] = esq[by * 128 + cl];
        col_j[j] = (unsigned)cl;
    }

    #pragma unroll
    for (int i = 0; i < 8; ++i) {
        #pragma unroll
        for (int r = 0; r < 4; ++r) {
            unsigned k[4];
            #pragma unroll
            for (int j = 0; j < 4; ++j) {
                unsigned iv = (unsigned)(esq_j[j] - acc[i][j][r]);
                k[j] = (iv << 7) | col_j[j];
            }
            unsigned lo1 = umin_(k[0], k[1]), hi1 = umax_(k[0], k[1]);
            unsigned lo2 = umin_(k[2], k[3]), hi2 = umax_(k[2], k[3]);
            unsigned k1 = umin_(lo1, lo2);
            unsigned k2 = umin_(umax_(lo1, lo2), umin_(hi1, hi2));
            int row = wm * 128 + i * 16 + lg * 4 + r;
            mb[row * 33 + wn * 16 + lr] =
                ((unsigned long long)k1 << 32) | k2;
        }
    }
    __syncthreads();

    // ---- epilogue pass 2: one row per thread, merge 32 sorted pairs ----
    {
        unsigned b1 = 0xFFFFFFFFu, b2 = 0xFFFFFFFFu;
        #pragma unroll 4
        for (int q = 0; q < 32; ++q) {
            unsigned long long e = mb[t * 33 + q];
            unsigned e1 = (unsigned)(e >> 32), e2 = (unsigned)e;
            unsigned nb1 = umin_(b1, e1);
            b2 = umin_(umax_(b1, e1), umin_(b2, e2));
            b1 = nb1;
        }
        tab[((size_t)(bx * 256 + t)) * 64 + by] =
            ((unsigned long long)b1 << 32) | b2;
    }
}

// ---------------------------------------------------------------------------
// K2: fused collect + exact fp32 rescore -> rowkey (ws). R15-proven.
// Writes ONLY ws (rowkey) — tab (in d_out) is fully consumed before any
// kernel writes outq (the R16-R18 tab/outq aliasing race is eliminated by
// the kernel boundary).
// ---------------------------------------------------------------------------
__global__ __launch_bounds__(256)
void collect_rescore_kernel(const float* __restrict__ z,
                            const float* __restrict__ emb,
                            const float* __restrict__ esf,
                            const unsigned long long* __restrict__ tab,
                            unsigned long long* __restrict__ rowkey)
{
    int t = threadIdx.x, lane = t & 63;
    int row = blockIdx.x * 4 + (t >> 6);

    unsigned long long e = tab[(size_t)row * 64 + lane];
    unsigned k1 = (unsigned)(e >> 32), k2 = (unsigned)e;
    unsigned m = k1;
    #pragma unroll
    for (int mask = 1; mask <= 32; mask <<= 1) {
        unsigned o = (unsigned)__shfl_xor((int)m, mask, 64);
        m = umin_(m, o);
    }
    unsigned thr = m + ((unsigned)DELTA_INT << 7);
    unsigned long long m1 = __ballot(k1 <= thr);
    unsigned long long m2 = __ballot(k2 <= thr);

    const float4* zr = (const float4*)(z + (size_t)row * DIMS + lane * 8);
    float4 a0 = zr[0], a1 = zr[1];

    unsigned long long best = ~0ull;
    while (m1 | m2) {
        int src;
        unsigned kk;
        if (m1) {
            src = __ffsll((long long)m1) - 1;
            m1 &= m1 - 1;
            kk = (unsigned)__shfl((int)k1, src, 64);
        } else {
            src = __ffsll((long long)m2) - 1;
            m2 &= m2 - 1;
            kk = (unsigned)__shfl((int)k2, src, 64);
        }
        int col = src * 128 + (int)(kk & 127u);

        const float4* er = (const float4*)(emb + (size_t)col * DIMS + lane * 8);
        float4 b0 = er[0], b1v = er[1];
        float s = a0.x * b0.x;
        s = fmaf(a0.y, b0.y, s); s = fmaf(a0.z, b0.z, s);
        s = fmaf(a0.w, b0.w, s); s = fmaf(a1.x, b1v.x, s);
        s = fmaf(a1.y, b1v.y, s); s = fmaf(a1.z, b1v.z, s);
        s = fmaf(a1.w, b1v.w, s);
        #pragma unroll
        for (int mask = 32; mask; mask >>= 1) s += __shfl_xor(s, mask);
        float v = fmaf(-2.f, s, esf[col]);
        unsigned long long key =
            ((unsigned long long)fkey(v) << 32) | (unsigned)col;
        best = key < best ? key : best;
    }
    if (lane == 0) rowkey[row] = best;
}

// ---------------------------------------------------------------------------
// K3: gather + loss partials + index output + histogram + (last block only)
// finalize. R15-proven gather path; finalize fused via done counter
// (release: __threadfence before atomicAdd; acquire: __threadfence in last
// block). Gather reads only rowkey/emb/z (no tab) — safe to overwrite the
// d_out scratch regions.
// ---------------------------------------------------------------------------
__global__ __launch_bounds__(256)
void gather_loss_kernel(const float* __restrict__ z, const float* __restrict__ emb,
                        const unsigned long long* __restrict__ rowkey,
                        float* __restrict__ outq, float* __restrict__ out_idx_f,
                        int* __restrict__ counts, float* __restrict__ bsums,
                        int* __restrict__ done, float* __restrict__ out_scalars)
{
    int gid = blockIdx.x * 256 + threadIdx.x;
    int row = gid >> 7;
    int c4  = (gid & 127) << 2;
    int idx = (int)(rowkey[row] & 0xFFFFFFFFull);
    if ((gid & 127) == 0) {
        out_idx_f[row] = (float)idx;
        atomicAdd(&counts[idx], 1);
    }
    float4 e  = *(const float4*)&emb[(size_t)idx * DIMS + c4];
    float4 zv = *(const float4*)&z[(size_t)row * DIMS + c4];
    *(float4*)&outq[(size_t)row * DIMS + c4] = e;
    float dx = e.x - zv.x, dy = e.y - zv.y, dz = e.z - zv.z, dw = e.w - zv.w;
    float s = dx * dx + dy * dy + dz * dz + dw * dw;
    #pragma unroll
    for (int off = 32; off; off >>= 1) s += __shfl_down(s, off);
    __shared__ float wsum[4];
    __shared__ int lastFlag;
    if ((threadIdx.x & 63) == 0) wsum[threadIdx.x >> 6] = s;
    __syncthreads();
    if (threadIdx.x == 0) {
        bsums[blockIdx.x] = wsum[0] + wsum[1] + wsum[2] + wsum[3];
        __threadfence();                        // release
        lastFlag = (atomicAdd(done, 1) == 8191);
    }
    __syncthreads();

    if (lastFlag) {
        __threadfence();                        // acquire
        int t = threadIdx.x;
        double lsum = 0.0, psum = 0.0;
        for (int i = t; i < 8192; i += 256) {
            lsum += (double)bsums[i];
            double avg = (double)counts[i] * (1.0 / 16384.0);
            psum += avg * log(avg + 1e-10);
        }
        #pragma unroll
        for (int off = 32; off; off >>= 1) {
            lsum += __shfl_down(lsum, off);
            psum += __shfl_down(psum, off);
        }
        __shared__ double l4[4], p4[4];
        if ((t & 63) == 0) { l4[t >> 6] = lsum; p4[t >> 6] = psum; }
        __syncthreads();
        if (t == 0) {
            double L = l4[0] + l4[1] + l4[2] + l4[3];
            double P = p4[0] + p4[1] + p4[2] + p4[3];
            out_scalars[0] = (float)(1.25 * L / 8388608.0);
            out_scalars[1] = (float)exp(-P);
        }
    }
}

// ---------------------------------------------------------------------------
// ws layout (bytes):
//   rowkey u64[16384] @ 0      (131072)  (written by collect_rescore)
//   counts int[8192]  @ 131072 (32768)   (zeroed by prep)
//   bsums  f32[8192]  @ 163840 (32768)
//   esf    f32[8192]  @ 196608 (32768)
//   esq    i32[8192]  @ 229376 (32768)
//   done   int        @ 262144 (4)       (zeroed by prep)
// d_out scratch reuse (all consumed BEFORE gather overwrites — kernel
// boundaries enforce ordering; no concurrent read/write aliasing):
//   zi8 @ 0 (8MB) | ei8 @ 16777216 (4MB) | tab @ 25165824 (8MB)
// d_out final (floats): quantized[8388608] | vq_loss | perplexity | idx[16384]
// ---------------------------------------------------------------------------
extern "C" void kernel_launch(void* const* d_in, const int* in_sizes, int n_in,
                              void* d_out, int out_size, void* d_ws, size_t ws_size,
                              hipStream_t stream)
{
    const float* z   = (const float*)d_in[0];
    const float* emb = (const float*)d_in[1];

    float* out         = (float*)d_out;
    float* outq        = out;
    float* out_scalars = out + 8388608;
    float* out_idx     = out + 8388610;

    char* ob = (char*)d_out;
    signed char* zi8 = (signed char*)(ob + 0);
    signed char* ei8 = (signed char*)(ob + 16777216);
    unsigned long long* tab = (unsigned long long*)(ob + 25165824);

    char* ws = (char*)d_ws;
    unsigned long long* rowkey = (unsigned long long*)(ws + 0);
    int*   counts = (int*)  (ws + 131072);
    float* bsums  = (float*)(ws + 163840);
    float* esf    = (float*)(ws + 196608);
    int*   esq    = (int*)  (ws + 229376);
    int*   done   = (int*)  (ws + 262144);

    prep_kernel<<<2816, 256, 0, stream>>>(z, emb, zi8, ei8, esf, esq,
                                          counts, done);
    screen_kernel<<<dim3(64, 64), 256, 0, stream>>>((const char*)zi8,
                                                    (const char*)ei8, esq, tab);
    collect_rescore_kernel<<<4096, 256, 0, stream>>>(z, emb, esf, tab, rowkey);
    gather_loss_kernel<<<8192, 256, 0, stream>>>(z, emb, rowkey, outq, out_idx,
                                                 counts, bsums, done,
                                                 out_scalars);
}

// Round 20
// 132.360 us; speedup vs baseline: 2.7632x; 2.7632x over previous
//
#include <hip/hip_runtime.h>
#include <math.h>

typedef int   i32x4 __attribute__((ext_vector_type(4)));

#define NROWS 16384
#define DIMS  512
#define KC    8192
#define QCLIP 4.5f
#define DELTA_INT 1992        // ceil(5.0 / (2*(4.5/127)^2)) grid units
#define IBIAS 16777216        // 2^24 bias so keys are non-negative

__device__ inline unsigned fkey(float v) {
    unsigned u = __float_as_uint(v);
    return (u & 0x80000000u) ? ~u : (u | 0x80000000u);
}
__device__ inline unsigned umin_(unsigned a, unsigned b) { return a < b ? a : b; }
__device__ inline unsigned umax_(unsigned a, unsigned b) { return a > b ? a : b; }

// ---------------------------------------------------------------------------
// K0: fused prep (R13-R15-proven). blocks [0,512): quantize z -> i8 panels;
// [512,768): quantize emb; [768,2816): emb row sum-of-squares in fp64 ->
// esf (f32) and esq (int grid). Blocks [0,32) zero the histogram.
// Packed i8 layout (bytes): p*131072 + s*16384 + c*16, chunk c = f*64+lg*16+rr.
// 1KB fragment chunk read at +lane*16 is lane-linear.
// ---------------------------------------------------------------------------
__global__ __launch_bounds__(256)
void prep_kernel(const float* __restrict__ z, const float* __restrict__ emb,
                 signed char* __restrict__ zi8, signed char* __restrict__ ei8,
                 float* __restrict__ esf, int* __restrict__ esq,
                 int* __restrict__ counts)
{
    const float QS = 127.0f / QCLIP;
    int b = blockIdx.x, t = threadIdx.x;
    if (b < 768) {
        if (b < 32) counts[b * 256 + t] = 0;
        const float* src;
        signed char* dst;
        int pb;
        if (b < 512) { src = z;   dst = zi8; pb = b; }
        else         { src = emb; dst = ei8; pb = b - 512; }
        int p = pb >> 3, s = pb & 7;
        signed char* dbase = dst + (size_t)p * 131072 + s * 16384;
        #pragma unroll
        for (int q = 0; q < 4; ++q) {
            int c = q * 256 + t;
            int f = c >> 6, lg = (c >> 4) & 3, rr = c & 15;
            int row = p * 256 + f * 16 + rr;
            const float* sp = src + (size_t)row * DIMS + s * 64 + lg * 16;
            float4 v0 = *(const float4*)(sp + 0);
            float4 v1 = *(const float4*)(sp + 4);
            float4 v2 = *(const float4*)(sp + 8);
            float4 v3 = *(const float4*)(sp + 12);
            float vv[16] = {v0.x, v0.y, v0.z, v0.w, v1.x, v1.y, v1.z, v1.w,
                            v2.x, v2.y, v2.z, v2.w, v3.x, v3.y, v3.z, v3.w};
            unsigned w[4];
            #pragma unroll
            for (int k = 0; k < 4; ++k) {
                unsigned r = 0;
                #pragma unroll
                for (int e = 0; e < 4; ++e) {
                    int qv = __float2int_rn(
                        fminf(fmaxf(vv[k * 4 + e] * QS, -127.f), 127.f));
                    r |= (unsigned)(qv & 255) << (e * 8);
                }
                w[k] = r;
            }
            *(i32x4*)(dbase + c * 16) =
                (i32x4){(int)w[0], (int)w[1], (int)w[2], (int)w[3]};
        }
    } else {
        int b2 = b - 768;
        int w = b2 * 4 + (t >> 6);
        int lane = t & 63;
        const float* r = emb + (size_t)w * DIMS;
        float4 v0 = *(const float4*)(r + lane * 4);
        float4 v1 = *(const float4*)(r + 256 + lane * 4);
        double s = (double)v0.x * v0.x + (double)v0.y * v0.y +
                   (double)v0.z * v0.z + (double)v0.w * v0.w +
                   (double)v1.x * v1.x + (double)v1.y * v1.y +
                   (double)v1.z * v1.z + (double)v1.w * v1.w;
        #pragma unroll
        for (int off = 32; off; off >>= 1) s += __shfl_down(s, off);
        if (lane == 0) {
            esf[w] = (float)s;
            const double grid = 2.0 * (QCLIP / 127.0) * (QCLIP / 127.0);
            esq[w] = (int)(s / grid + 0.5) + IBIAS;
        }
    }
}

// ---------------------------------------------------------------------------
// K1: i8 screen GEMM + per-(row, 128-col-block) top-2, INTEGER keys.
// Measured optimum (R14/R15, unchanged): 256x128 block, 4 waves 2Mx2N,
// wave tile 128x64, mfma_i32_16x16x64_i8, 8 K-steps, dbuf 48KB, 2 blocks/CU,
// bx on the fast grid axis. Fragment reads lane-linear: conflict-free.
// Epilogue: key = (esq[col] - dot) << 7 | col_local. tab u64 = k1<<32 | k2.
// ---------------------------------------------------------------------------
__global__ __launch_bounds__(256, 2)
void screen_kernel(const char* __restrict__ zq, const char* __restrict__ eq,
                   const int* __restrict__ esq,
                   unsigned long long* __restrict__ tab)
{
    __shared__ char smem[67584];   // dbuf 2x24KB; epilogue table 66KB

    const int t    = threadIdx.x;
    const int lane = t & 63;
    const int wave = t >> 6;
    const int lg   = lane >> 4;
    const int lr   = lane & 15;
    const int wm   = wave >> 1;      // 0..1 row half (128 rows)
    const int wn   = wave & 1;       // 0..1 col half (64 cols)
    const int bx   = blockIdx.x;     // row block 0..63 (FAST dim)
    const int by   = blockIdx.y;     // col block 0..63 (slow dim)

    const char* gA = zq + (size_t)bx * 131072;
    const char* gB = eq + (size_t)(by >> 1) * 131072 + (by & 1) * 8192;

    i32x4 acc[8][4];
    #pragma unroll
    for (int i = 0; i < 8; ++i)
        #pragma unroll
        for (int j = 0; j < 4; ++j)
            acc[i][j] = (i32x4){0, 0, 0, 0};

    typedef const __attribute__((address_space(1))) unsigned int gq_t;
    typedef __attribute__((address_space(3))) unsigned int lq_t;
    #define STAGE(dstbuf, s)                                                  \
    {                                                                         \
        const char* gsA = gA + (size_t)(s) * 16384;                          \
        const char* gsB = gB + (size_t)(s) * 16384;                          \
        _Pragma("unroll")                                                     \
        for (int k = 0; k < 4; ++k) {                                        \
            int off = k * 4096 + wave * 1024;                                \
            __builtin_amdgcn_global_load_lds(                                 \
                (gq_t*)(gsA + off + lane * 16),                               \
                (lq_t*)((dstbuf) + off), 16, 0, 0);                           \
        }                                                                     \
        _Pragma("unroll")                                                     \
        for (int k = 0; k < 2; ++k) {                                        \
            int off = k * 4096 + wave * 1024;                                \
            __builtin_amdgcn_global_load_lds(                                 \
                (gq_t*)(gsB + off + lane * 16),                               \
                (lq_t*)((dstbuf) + 16384 + off), 16, 0, 0);                   \
        }                                                                     \
    }
    #define COMPUTE(buf)                                                      \
    {                                                                         \
        const char* Ab = (buf) + (wm * 8) * 1024 + lane * 16;                 \
        const char* Bb = (buf) + 16384 + (wn * 4) * 1024 + lane * 16;         \
        i32x4 af[8], bf[4];                                                   \
        _Pragma("unroll")                                                     \
        for (int i = 0; i < 8; ++i) af[i] = *(const i32x4*)(Ab + i * 1024);   \
        _Pragma("unroll")                                                     \
        for (int j = 0; j < 4; ++j) bf[j] = *(const i32x4*)(Bb + j * 1024);   \
        _Pragma("unroll")                                                     \
        for (int i = 0; i < 8; ++i)                                           \
            _Pragma("unroll")                                                 \
            for (int j = 0; j < 4; ++j)                                       \
                acc[i][j] = __builtin_amdgcn_mfma_i32_16x16x64_i8(            \
                    af[i], bf[j], acc[i][j], 0, 0, 0);                        \
    }

    char* p0 = smem;
    char* p1 = smem + 24576;
    STAGE(p0, 0);
    __syncthreads();

    #pragma unroll 1
    for (int s = 0; s < 8; s += 2) {
        STAGE(p1, s + 1);
        COMPUTE(p0);
        __syncthreads();
        if (s + 2 < 8) STAGE(p0, s + 2);
        COMPUTE(p1);
        __syncthreads();
    }

    // ---- epilogue pass 1: per-thread top-2-of-4, integer keys ----
    unsigned long long* mb = (unsigned long long*)smem;  // stride 33/row
    int      esq_j[4];
    unsigned col_j[4];
    #pragma unroll
    for (int j = 0; j < 4; ++j) {
        int cl = wn * 64 + j * 16 + lr;
        esq_j[j] = esq[by * 128 + cl];
        col_j[j] = (unsigned)cl;
    }

    #pragma unroll
    for (int i = 0; i < 8; ++i) {
        #pragma unroll
        for (int r = 0; r < 4; ++r) {
            unsigned k[4];
            #pragma unroll
            for (int j = 0; j < 4; ++j) {
                unsigned iv = (unsigned)(esq_j[j] - acc[i][j][r]);
                k[j] = (iv << 7) | col_j[j];
            }
            unsigned lo1 = umin_(k[0], k[1]), hi1 = umax_(k[0], k[1]);
            unsigned lo2 = umin_(k[2], k[3]), hi2 = umax_(k[2], k[3]);
            unsigned k1 = umin_(lo1, lo2);
            unsigned k2 = umin_(umax_(lo1, lo2), umin_(hi1, hi2));
            int row = wm * 128 + i * 16 + lg * 4 + r;
            mb[row * 33 + wn * 16 + lr] =
                ((unsigned long long)k1 << 32) | k2;
        }
    }
    __syncthreads();

    // ---- epilogue pass 2: one row per thread, merge 32 sorted pairs ----
    {
        unsigned b1 = 0xFFFFFFFFu, b2 = 0xFFFFFFFFu;
        #pragma unroll 4
        for (int q = 0; q < 32; ++q) {
            unsigned long long e = mb[t * 33 + q];
            unsigned e1 = (unsigned)(e >> 32), e2 = (unsigned)e;
            unsigned nb1 = umin_(b1, e1);
            b2 = umin_(umax_(b1, e1), umin_(b2, e2));
            b1 = nb1;
        }
        tab[((size_t)(bx * 256 + t)) * 64 + by] =
            ((unsigned long long)b1 << 32) | b2;
    }
}

// ---------------------------------------------------------------------------
// K2: fused collect + exact fp32 rescore -> rowkey (ws only; tab fully
// consumed before any kernel writes outq — kernel boundary kills the
// tab/outq aliasing race).
// ---------------------------------------------------------------------------
__global__ __launch_bounds__(256)
void collect_rescore_kernel(const float* __restrict__ z,
                            const float* __restrict__ emb,
                            const float* __restrict__ esf,
                            const unsigned long long* __restrict__ tab,
                            unsigned long long* __restrict__ rowkey)
{
    int t = threadIdx.x, lane = t & 63;
    int row = blockIdx.x * 4 + (t >> 6);

    unsigned long long e = tab[(size_t)row * 64 + lane];
    unsigned k1 = (unsigned)(e >> 32), k2 = (unsigned)e;
    unsigned m = k1;
    #pragma unroll
    for (int mask = 1; mask <= 32; mask <<= 1) {
        unsigned o = (unsigned)__shfl_xor((int)m, mask, 64);
        m = umin_(m, o);
    }
    unsigned thr = m + ((unsigned)DELTA_INT << 7);
    unsigned long long m1 = __ballot(k1 <= thr);
    unsigned long long m2 = __ballot(k2 <= thr);

    const float4* zr = (const float4*)(z + (size_t)row * DIMS + lane * 8);
    float4 a0 = zr[0], a1 = zr[1];

    unsigned long long best = ~0ull;
    while (m1 | m2) {
        int src;
        unsigned kk;
        if (m1) {
            src = __ffsll((long long)m1) - 1;
            m1 &= m1 - 1;
            kk = (unsigned)__shfl((int)k1, src, 64);
        } else {
            src = __ffsll((long long)m2) - 1;
            m2 &= m2 - 1;
            kk = (unsigned)__shfl((int)k2, src, 64);
        }
        int col = src * 128 + (int)(kk & 127u);

        const float4* er = (const float4*)(emb + (size_t)col * DIMS + lane * 8);
        float4 b0 = er[0], b1v = er[1];
        float s = a0.x * b0.x;
        s = fmaf(a0.y, b0.y, s); s = fmaf(a0.z, b0.z, s);
        s = fmaf(a0.w, b0.w, s); s = fmaf(a1.x, b1v.x, s);
        s = fmaf(a1.y, b1v.y, s); s = fmaf(a1.z, b1v.z, s);
        s = fmaf(a1.w, b1v.w, s);
        #pragma unroll
        for (int mask = 32; mask; mask >>= 1) s += __shfl_xor(s, mask);
        float v = fmaf(-2.f, s, esf[col]);
        unsigned long long key =
            ((unsigned long long)fkey(v) << 32) | (unsigned)col;
        best = key < best ? key : best;
    }
    if (lane == 0) rowkey[row] = best;
}

// ---------------------------------------------------------------------------
// K3: gather + loss partials + index output + histogram (R15-proven; no
// fences, no done counter — the fused-finalize tail cost 260 us in R19).
// ---------------------------------------------------------------------------
__global__ __launch_bounds__(256)
void gather_loss_kernel(const float* __restrict__ z, const float* __restrict__ emb,
                        const unsigned long long* __restrict__ rowkey,
                        float* __restrict__ outq, float* __restrict__ out_idx_f,
                        int* __restrict__ counts, float* __restrict__ bsums)
{
    int gid = blockIdx.x * 256 + threadIdx.x;
    int row = gid >> 7;
    int c4  = (gid & 127) << 2;
    int idx = (int)(rowkey[row] & 0xFFFFFFFFull);
    if ((gid & 127) == 0) {
        out_idx_f[row] = (float)idx;
        atomicAdd(&counts[idx], 1);
    }
    float4 e  = *(const float4*)&emb[(size_t)idx * DIMS + c4];
    float4 zv = *(const float4*)&z[(size_t)row * DIMS + c4];
    *(float4*)&outq[(size_t)row * DIMS + c4] = e;
    float dx = e.x - zv.x, dy = e.y - zv.y, dz = e.z - zv.z, dw = e.w - zv.w;
    float s = dx * dx + dy * dy + dz * dz + dw * dw;
    #pragma unroll
    for (int off = 32; off; off >>= 1) s += __shfl_down(s, off);
    __shared__ float wsum[4];
    if ((threadIdx.x & 63) == 0) wsum[threadIdx.x >> 6] = s;
    __syncthreads();
    if (threadIdx.x == 0)
        bsums[blockIdx.x] = wsum[0] + wsum[1] + wsum[2] + wsum[3];
}

// ---------------------------------------------------------------------------
// K4: finalize scalars: vq_loss and perplexity (separate tiny dispatch).
// ---------------------------------------------------------------------------
__global__ __launch_bounds__(256)
void finalize_kernel(const int* __restrict__ counts, const float* __restrict__ bsums,
                     float* __restrict__ out_scalars)
{
    int t = threadIdx.x;
    double ls = 0.0, ps = 0.0;
    for (int i = t; i < 8192; i += 256) {
        ls += (double)bsums[i];
        double avg = (double)counts[i] * (1.0 / 16384.0);
        ps += avg * log(avg + 1e-10);
    }
    #pragma unroll
    for (int off = 32; off; off >>= 1) {
        ls += __shfl_down(ls, off);
        ps += __shfl_down(ps, off);
    }
    __shared__ double l4[4], p4[4];
    if ((t & 63) == 0) { l4[t >> 6] = ls; p4[t >> 6] = ps; }
    __syncthreads();
    if (t == 0) {
        double L = l4[0] + l4[1] + l4[2] + l4[3];
        double P = p4[0] + p4[1] + p4[2] + p4[3];
        out_scalars[0] = (float)(1.25 * L / 8388608.0);
        out_scalars[1] = (float)exp(-P);
    }
}

// ---------------------------------------------------------------------------
// ws layout (bytes):
//   rowkey u64[16384] @ 0      (131072)  (written by collect_rescore)
//   counts int[8192]  @ 131072 (32768)   (zeroed by prep)
//   bsums  f32[8192]  @ 163840 (32768)
//   esf    f32[8192]  @ 196608 (32768)
//   esq    i32[8192]  @ 229376 (32768)
// d_out scratch reuse (all consumed BEFORE gather overwrites — kernel
// boundaries enforce ordering):
//   zi8 @ 0 (8MB) | ei8 @ 16777216 (4MB) | tab @ 25165824 (8MB)
// d_out final (floats): quantized[8388608] | vq_loss | perplexity | idx[16384]
// ---------------------------------------------------------------------------
extern "C" void kernel_launch(void* const* d_in, const int* in_sizes, int n_in,
                              void* d_out, int out_size, void* d_ws, size_t ws_size,
                              hipStream_t stream)
{
    const float* z   = (const float*)d_in[0];
    const float* emb = (const float*)d_in[1];

    float* out         = (float*)d_out;
    float* outq        = out;
    float* out_scalars = out + 8388608;
    float* out_idx     = out + 8388610;

    char* ob = (char*)d_out;
    signed char* zi8 = (signed char*)(ob + 0);
    signed char* ei8 = (signed char*)(ob + 16777216);
    unsigned long long* tab = (unsigned long long*)(ob + 25165824);

    char* ws = (char*)d_ws;
    unsigned long long* rowkey = (unsigned long long*)(ws + 0);
    int*   counts = (int*)  (ws + 131072);
    float* bsums  = (float*)(ws + 163840);
    float* esf    = (float*)(ws + 196608);
    int*   esq    = (int*)  (ws + 229376);

    prep_kernel<<<2816, 256, 0, stream>>>(z, emb, zi8, ei8, esf, esq, counts);
    screen_kernel<<<dim3(64, 64), 256, 0, stream>>>((const char*)zi8,
                                                    (const char*)ei8, esq, tab);
    collect_rescore_kernel<<<4096, 256, 0, stream>>>(z, emb, esf, tab, rowkey);
    gather_loss_kernel<<<8192, 256, 0, stream>>>(z, emb, rowkey, outq, out_idx,
                                                 counts, bsums);
    finalize_kernel<<<1, 256, 0, stream>>>(counts, bsums, out_scalars);
}